// Round 8
// baseline (447.853 us; speedup 1.0000x reference)
//
#include <hip/hip_runtime.h>

// Inverse 2D DWT, single level, fused column+row synthesis. FP32 throughout.
// R8 = union of the three individually-validated pieces:
//  (1) full-line store layout (R5): lane owns 2 input cols -> its 4 output
//      cols are one contiguous 16B chunk; one dwordx4 per output row gives a
//      contiguous 1KB wave span, every 64B line fully written by ONE instr.
//  (2) nontemporal stores (R2): write-only output stops evicting L3-resident
//      input (R2 measured FETCH 195->147MB). R2's +18% write amplification
//      came from 16B-granule partial lines -- impossible here thanks to (1).
//  (3) whole-strip burst preload (R7, best kernel so far): per-stream
//      contiguous 8-10KB bursts, all loads in flight before compute.
// Seam halo (col 127/128) via wave-uniform scalar loads + redundant seam
// synthesis; image-edge reflects are lane-local.
// out[2i+py][2j+px] = sum_{dy,dx in {-1,0,1}}
//   wh[py][dy]*wh[px][dx]*ss + wg[py][dy]*wh[px][dx]*sd
// + wh[py][dy]*wg[px][dx]*ds + wg[py][dy]*wg[px][dx]*dd
// with wh[0] = (h4,h2,h0), wh[1] = (h5,h3,h1) over dy=(-1,0,+1); reflect pad 1.

typedef float float2v __attribute__((ext_vector_type(2)));
typedef float float4v __attribute__((ext_vector_type(4)));

constexpr int Hc = 256;
constexpr int Wc = 256;
constexpr int ROWS = 8;   // rows per wave strip
constexpr int TW   = 128; // input cols per wave tile (2 tiles per image)

__global__ __launch_bounds__(256) void idwt_kernel(
    const float* __restrict__ ss, const float* __restrict__ sd,
    const float* __restrict__ ds, const float* __restrict__ dd,
    const float* __restrict__ hf, const float* __restrict__ gf,
    float* __restrict__ out)
{
    const int lane = threadIdx.x;        // 0..63
    const int wv   = threadIdx.y;        // 0..3
    const int tile = wv & 1;             // 0 = cols [0,128), 1 = cols [128,256)
    const int rs   = wv >> 1;            // row-strip within block (0..1)
    const int i0   = (blockIdx.x * 2 + rs) * ROWS;
    const int bc   = blockIdx.y;         // 0..B*C-1

    const float h0 = hf[0], h1 = hf[1], h2 = hf[2];
    const float h3 = hf[3], h4 = hf[4], h5 = hf[5];
    const float g0 = gf[0], g1 = gf[1], g2 = gf[2];
    const float g3 = gf[3], g4 = gf[4], g5 = gf[5];

    const size_t off = (size_t)bc * (Hc * Wc);
    const int c0 = tile * TW + 2 * lane;       // this lane's first input col
    const float* pss = ss + off;
    const float* psd = sd + off;
    const float* pds = ds + off;
    const float* pdd = dd + off;

    auto ld2 = [&](const float* p, int r) -> float2v {
        return *reinterpret_cast<const float2v*>(p + (size_t)r * Wc + c0);
    };
    // seam column: left tile needs col 128, right tile needs col 127.
    // Wave-uniform address -> broadcast from one hot line.
    const int seam = tile ? (TW - 1) : TW;
    auto lde = [&](const float* p, int r) -> float {
        return p[(size_t)r * Wc + seam];
    };

    // ---- whole-strip burst preload ----
    // index 0 = row i0-1 (reflect at top), 1+k = row i0+k, ROWS+1 = row i0+ROWS
    // (reflect at bottom). All indices compile-time under full unroll.
    const int rm = (i0 == 0) ? 1 : i0 - 1;
    const int rp = (i0 + ROWS < Hc) ? i0 + ROWS : Hc - 2;

    float2v S[ROWS + 2], T[ROWS + 2], U[ROWS + 2], V[ROWS + 2];
    float  eS[ROWS + 2], eT[ROWS + 2], eU[ROWS + 2], eV[ROWS + 2];

    S[0] = ld2(pss, rm);
    #pragma unroll
    for (int k = 0; k < ROWS; ++k) S[1 + k] = ld2(pss, i0 + k);
    S[ROWS + 1] = ld2(pss, rp);
    T[0] = ld2(psd, rm);
    #pragma unroll
    for (int k = 0; k < ROWS; ++k) T[1 + k] = ld2(psd, i0 + k);
    T[ROWS + 1] = ld2(psd, rp);
    U[0] = ld2(pds, rm);
    #pragma unroll
    for (int k = 0; k < ROWS; ++k) U[1 + k] = ld2(pds, i0 + k);
    U[ROWS + 1] = ld2(pds, rp);
    V[0] = ld2(pdd, rm);
    #pragma unroll
    for (int k = 0; k < ROWS; ++k) V[1 + k] = ld2(pdd, i0 + k);
    V[ROWS + 1] = ld2(pdd, rp);

    eS[0] = lde(pss, rm);
    #pragma unroll
    for (int k = 0; k < ROWS; ++k) eS[1 + k] = lde(pss, i0 + k);
    eS[ROWS + 1] = lde(pss, rp);
    eT[0] = lde(psd, rm);
    #pragma unroll
    for (int k = 0; k < ROWS; ++k) eT[1 + k] = lde(psd, i0 + k);
    eT[ROWS + 1] = lde(psd, rp);
    eU[0] = lde(pds, rm);
    #pragma unroll
    for (int k = 0; k < ROWS; ++k) eU[1 + k] = lde(pds, i0 + k);
    eU[ROWS + 1] = lde(pds, rp);
    eV[0] = lde(pdd, rm);
    #pragma unroll
    for (int k = 0; k < ROWS; ++k) eV[1 + k] = lde(pdd, i0 + k);
    eV[ROWS + 1] = lde(pdd, rp);

    // Pin the schedule: no sinking loads below / hoisting compute above.
    __builtin_amdgcn_sched_barrier(0);

    const int W2 = 2 * Wc;
    float* obase = out + (size_t)bc * (2 * Hc) * W2 + tile * (2 * TW) + 4 * lane;

    #pragma unroll
    for (int r = 0; r < ROWS; ++r) {
        const int i = i0 + r;

        // vertical (column) synthesis for this lane's 2 columns
        float2v vs0, vs1, vd0, vd1;
        #pragma unroll
        for (int k = 0; k < 2; ++k) {
            vs0[k] = h4*S[r][k] + h2*S[r+1][k] + h0*S[r+2][k] + g4*T[r][k] + g2*T[r+1][k] + g0*T[r+2][k];
            vs1[k] = h5*S[r][k] + h3*S[r+1][k] + h1*S[r+2][k] + g5*T[r][k] + g3*T[r+1][k] + g1*T[r+2][k];
            vd0[k] = h4*U[r][k] + h2*U[r+1][k] + h0*U[r+2][k] + g4*V[r][k] + g2*V[r+1][k] + g0*V[r+2][k];
            vd1[k] = h5*U[r][k] + h3*U[r+1][k] + h1*U[r+2][k] + g5*V[r][k] + g3*V[r+1][k] + g1*V[r+2][k];
        }
        // seam column vertical synthesis (redundant across lanes, 24 FMA)
        const float sS0 = h4*eS[r] + h2*eS[r+1] + h0*eS[r+2] + g4*eT[r] + g2*eT[r+1] + g0*eT[r+2];
        const float sS1 = h5*eS[r] + h3*eS[r+1] + h1*eS[r+2] + g5*eT[r] + g3*eT[r+1] + g1*eT[r+2];
        const float sD0 = h4*eU[r] + h2*eU[r+1] + h0*eU[r+2] + g4*eV[r] + g2*eV[r+1] + g0*eV[r+2];
        const float sD1 = h5*eU[r] + h3*eU[r+1] + h1*eU[r+2] + g5*eV[r] + g3*eV[r+1] + g1*eV[r+2];

        // horizontal neighbors: interior via shuffle; lane 0 / lane 63 take
        // image-edge reflect (lane-local) or the seam value.
        auto lnb = [&](const float2v& v, float sv) -> float {
            float x = __shfl_up(v[1], 1);
            return (lane == 0) ? (tile ? sv : v[1]) : x;   // col -1 -> col 1
        };
        auto rnb = [&](const float2v& v, float sv) -> float {
            float x = __shfl_down(v[0], 1);
            return (lane == 63) ? (tile ? v[0] : sv) : x;  // col 256 -> col 254
        };
        const float La = lnb(vs0, sS0), Ra = rnb(vs0, sS0);
        const float Lb = lnb(vd0, sD0), Rb = rnb(vd0, sD0);
        const float Lc = lnb(vs1, sS1), Rc = rnb(vs1, sS1);
        const float Ld = lnb(vd1, sD1), Rd = rnb(vd1, sD1);

        // horizontal (row) synthesis: lane's 4 contiguous output cols x 2 rows
        float4v o0, o1;
        o0[0] = h4*La      + h2*vs0[0] + h0*vs0[1] + g4*Lb      + g2*vd0[0] + g0*vd0[1];
        o0[1] = h5*La      + h3*vs0[0] + h1*vs0[1] + g5*Lb      + g3*vd0[0] + g1*vd0[1];
        o0[2] = h4*vs0[0]  + h2*vs0[1] + h0*Ra     + g4*vd0[0]  + g2*vd0[1] + g0*Rb;
        o0[3] = h5*vs0[0]  + h3*vs0[1] + h1*Ra     + g5*vd0[0]  + g3*vd0[1] + g1*Rb;
        o1[0] = h4*Lc      + h2*vs1[0] + h0*vs1[1] + g4*Ld      + g2*vd1[0] + g0*vd1[1];
        o1[1] = h5*Lc      + h3*vs1[0] + h1*vs1[1] + g5*Ld      + g3*vd1[0] + g1*vd1[1];
        o1[2] = h4*vs1[0]  + h2*vs1[1] + h0*Rc     + g4*vd1[0]  + g2*vd1[1] + g0*Rd;
        o1[3] = h5*vs1[0]  + h3*vs1[1] + h1*Rc     + g5*vd1[0]  + g3*vd1[1] + g1*Rd;

        // nontemporal full-line stores: one dwordx4 per output row per lane,
        // wave covers a contiguous 1KB span -> every 64B line fully written
        // by one instruction -> NT cannot cause partial-line amplification.
        float* orow0 = obase + (size_t)(2 * i) * W2;
        __builtin_nontemporal_store(o0, reinterpret_cast<float4v*>(orow0));
        __builtin_nontemporal_store(o1, reinterpret_cast<float4v*>(orow0 + W2));
    }
}

extern "C" void kernel_launch(void* const* d_in, const int* in_sizes, int n_in,
                              void* d_out, int out_size, void* d_ws, size_t ws_size,
                              hipStream_t stream) {
    const float* ss = (const float*)d_in[0];
    const float* sd = (const float*)d_in[1];
    const float* ds = (const float*)d_in[2];
    const float* dd = (const float*)d_in[3];
    const float* hf = (const float*)d_in[4];
    const float* gf = (const float*)d_in[5];
    float* out = (float*)d_out;

    const int BC = in_sizes[0] / (Hc * Wc);   // B*C = 256
    dim3 block(64, 4);                         // waves: 2 tiles x 2 row-strips
    dim3 grid(Hc / (ROWS * 2), BC);            // (16, 256)
    idwt_kernel<<<grid, block, 0, stream>>>(ss, sd, ds, dd, hf, gf, out);
}

// Round 9
// 439.437 us; speedup vs baseline: 1.0192x; 1.0192x over previous
//
#include <hip/hip_runtime.h>

// Inverse 2D DWT, single level, fused column+row synthesis. FP32 throughout.
// R9: STREAM-SPECIALIZED WAVES via LDS staging.
// R1-R8 scoreboard: burst preload +5% (R7 best); NT stores always lose (R2
// amplification, R8 slow NT path); MLP/occupancy/XCD/store-layout/row-phase
// all neutral at ~3.2 TB/s -- half of copy BW (6.3). Last structural
// difference vs a copy: each wave multiplexes FOUR read streams (buffers
// 2^26 B apart, set/channel-congruent) plus 8 ds_permute per row. Here each
// of a block's 4 waves reads exactly ONE stream -- a contiguous 10KB burst
// (10 x dwordx4-per-lane rows) staged to LDS -- then after one barrier each
// wave computes 2 rows reading all 4 streams from LDS. Per-wave global
// access is copy-identical: one stream, contiguous, 16B/lane.
// out[2i+py][2j+px] = sum_{dy,dx in {-1,0,1}}
//   wh[py][dy]*wh[px][dx]*ss + wg[py][dy]*wh[px][dx]*sd
// + wh[py][dy]*wg[px][dx]*ds + wg[py][dy]*wg[px][dx]*dd
// with wh[0] = (h4,h2,h0), wh[1] = (h5,h3,h1) over dy=(-1,0,+1); reflect pad 1.

typedef float float4v __attribute__((ext_vector_type(4)));

constexpr int Hc = 256;
constexpr int Wc = 256;
constexpr int ROWS = 8;          // rows per block
constexpr int NS   = ROWS + 2;   // staged rows incl. top/bottom halo

__global__ __launch_bounds__(256) void idwt_kernel(
    const float* __restrict__ ss, const float* __restrict__ sd,
    const float* __restrict__ ds, const float* __restrict__ dd,
    const float* __restrict__ hf, const float* __restrict__ gf,
    float* __restrict__ out)
{
    const int lane = threadIdx.x;            // 0..63
    const int wid  = threadIdx.y;            // 0..3 = stream id for staging
    const int i0   = blockIdx.x * ROWS;      // first row of this block
    const int bc   = blockIdx.y;             // 0..B*C-1

    __shared__ float lds[4][NS][Wc];         // 40 KB

    const float h0 = hf[0], h1 = hf[1], h2 = hf[2];
    const float h3 = hf[3], h4 = hf[4], h5 = hf[5];
    const float g0 = gf[0], g1 = gf[1], g2 = gf[2];
    const float g3 = gf[3], g4 = gf[4], g5 = gf[5];

    const size_t off = (size_t)bc * (Hc * Wc);

    // ---- stage: wave `wid` bursts its ONE stream into LDS ----
    const float* sbase =
        (wid == 0 ? ss : wid == 1 ? sd : wid == 2 ? ds : dd) + off + 4 * lane;

    const int rm = (i0 == 0) ? 1 : i0 - 1;                 // reflect-1 top
    const int rp = (i0 + ROWS < Hc) ? i0 + ROWS : Hc - 2;  // reflect-1 bottom

    float4v stg[NS];
    stg[0] = *reinterpret_cast<const float4v*>(sbase + (size_t)rm * Wc);
    #pragma unroll
    for (int k = 0; k < ROWS; ++k)
        stg[1 + k] = *reinterpret_cast<const float4v*>(sbase + (size_t)(i0 + k) * Wc);
    stg[NS - 1] = *reinterpret_cast<const float4v*>(sbase + (size_t)rp * Wc);

    #pragma unroll
    for (int s = 0; s < NS; ++s)
        *reinterpret_cast<float4v*>(&lds[wid][s][4 * lane]) = stg[s];

    __syncthreads();

    // ---- compute: wave `wid` produces input rows i0+2*wid, i0+2*wid+1 ----
    const int W2 = 2 * Wc;
    float* obase = out + (size_t)bc * (2 * Hc) * W2 + 8 * lane;

    // horizontal reflect at image edges:
    //   col -1 -> col 1 (lane 0: w[1]); col Wc -> col Wc-2 (lane 63: w[2])
    auto left = [&](const float4v& w) -> float {
        float l = __shfl_up(w[3], 1);
        return (lane == 0) ? w[1] : l;
    };
    auto right = [&](const float4v& w) -> float {
        float rr = __shfl_down(w[0], 1);
        return (lane == 63) ? w[2] : rr;
    };
    auto ldsrow = [&](int stream, int slot) -> float4v {
        return *reinterpret_cast<const float4v*>(&lds[stream][slot][4 * lane]);
    };

    #pragma unroll
    for (int rr = 0; rr < 2; ++rr) {
        const int local = 2 * wid + rr;      // row within strip, 0..7
        const int i = i0 + local;

        const float4v Sm = ldsrow(0, local), Sc = ldsrow(0, local + 1), Sp = ldsrow(0, local + 2);
        const float4v Tm = ldsrow(1, local), Tc = ldsrow(1, local + 1), Tp = ldsrow(1, local + 2);
        const float4v Um = ldsrow(2, local), Uc = ldsrow(2, local + 1), Up = ldsrow(2, local + 2);
        const float4v Vm = ldsrow(3, local), Vc = ldsrow(3, local + 1), Vp = ldsrow(3, local + 2);

        // vertical (column) synthesis for this wave's 4 columns
        float4v vs0, vs1, vd0, vd1;
        #pragma unroll
        for (int k = 0; k < 4; ++k) {
            vs0[k] = h4*Sm[k] + h2*Sc[k] + h0*Sp[k] + g4*Tm[k] + g2*Tc[k] + g0*Tp[k];
            vs1[k] = h5*Sm[k] + h3*Sc[k] + h1*Sp[k] + g5*Tm[k] + g3*Tc[k] + g1*Tp[k];
            vd0[k] = h4*Um[k] + h2*Uc[k] + h0*Up[k] + g4*Vm[k] + g2*Vc[k] + g0*Vp[k];
            vd1[k] = h5*Um[k] + h3*Uc[k] + h1*Up[k] + g5*Vm[k] + g3*Vc[k] + g1*Vp[k];
        }

        // 6-wide horizontal windows via shuffle (static indices only)
        const float a [6] = { left(vs0), vs0[0], vs0[1], vs0[2], vs0[3], right(vs0) };
        const float b [6] = { left(vd0), vd0[0], vd0[1], vd0[2], vd0[3], right(vd0) };
        const float c2[6] = { left(vs1), vs1[0], vs1[1], vs1[2], vs1[3], right(vs1) };
        const float d2[6] = { left(vd1), vd1[0], vd1[1], vd1[2], vd1[3], right(vd1) };

        // horizontal (row) synthesis: 2 output rows x 8 output cols
        float4v o00, o01, o10, o11;
        #pragma unroll
        for (int t = 0; t < 4; ++t) {
            const float e0 = h4*a [t] + h2*a [t+1] + h0*a [t+2] + g4*b [t] + g2*b [t+1] + g0*b [t+2];
            const float e1 = h5*a [t] + h3*a [t+1] + h1*a [t+2] + g5*b [t] + g3*b [t+1] + g1*b [t+2];
            const float f0 = h4*c2[t] + h2*c2[t+1] + h0*c2[t+2] + g4*d2[t] + g2*d2[t+1] + g0*d2[t+2];
            const float f1 = h5*c2[t] + h3*c2[t+1] + h1*c2[t+2] + g5*d2[t] + g3*d2[t+1] + g1*d2[t+2];
            if (t < 2) {
                o00[2*t]     = e0; o00[2*t+1]     = e1;
                o10[2*t]     = f0; o10[2*t+1]     = f1;
            } else {
                o01[2*(t-2)] = e0; o01[2*(t-2)+1] = e1;
                o11[2*(t-2)] = f0; o11[2*(t-2)+1] = f1;
            }
        }

        float* orow0 = obase + (size_t)(2 * i) * W2;
        float* orow1 = orow0 + W2;
        *reinterpret_cast<float4v*>(orow0)     = o00;
        *reinterpret_cast<float4v*>(orow0 + 4) = o01;
        *reinterpret_cast<float4v*>(orow1)     = o10;
        *reinterpret_cast<float4v*>(orow1 + 4) = o11;
    }
}

extern "C" void kernel_launch(void* const* d_in, const int* in_sizes, int n_in,
                              void* d_out, int out_size, void* d_ws, size_t ws_size,
                              hipStream_t stream) {
    const float* ss = (const float*)d_in[0];
    const float* sd = (const float*)d_in[1];
    const float* ds = (const float*)d_in[2];
    const float* dd = (const float*)d_in[3];
    const float* hf = (const float*)d_in[4];
    const float* gf = (const float*)d_in[5];
    float* out = (float*)d_out;

    const int BC = in_sizes[0] / (Hc * Wc);   // B*C = 256
    dim3 block(64, 4);                         // 4 waves: 1 stream each
    dim3 grid(Hc / ROWS, BC);                  // (32, 256)
    idwt_kernel<<<grid, block, 0, stream>>>(ss, sd, ds, dd, hf, gf, out);
}